// Round 1
// baseline (657.644 us; speedup 1.0000x reference)
//
#include <hip/hip_runtime.h>

#define N_NODES 100000
#define E_EDGES 800000
#define IN_F 256
#define D_HEAD 64
#define H_HEADS 4
#define EF_F 64
#define NET_T 8
#define HD 256          // H*D
#define SLOPE 0.2f

typedef unsigned short u16;
typedef unsigned long long u64;

static __device__ __forceinline__ u16 f2bf(float f) {
    unsigned int u = __float_as_uint(f);
    unsigned int r = u + 0x7FFFu + ((u >> 16) & 1u);
    return (u16)(r >> 16);
}
static __device__ __forceinline__ float bf2f(unsigned int u) {
    return __uint_as_float(u << 16);
}

// ---------------- K0: s_e[t][h] = sum_f a_e[h,f] * (edge_emb @ W_e)[t,h,f] ----------------
__global__ void k_se(const float* __restrict__ edge_emb, const float* __restrict__ W_e,
                     const float* __restrict__ a_e, float* __restrict__ s_e) {
    int tid = threadIdx.x;           // 256 threads
    int t  = tid >> 5;               // 0..7
    int h  = (tid >> 3) & 3;         // 0..3
    int fc = tid & 7;                // 0..7
    float part = 0.f;
    for (int j = 0; j < 8; ++j) {
        int f = fc * 8 + j;
        float acc = 0.f;
        for (int k = 0; k < EF_F; ++k)
            acc += edge_emb[t * EF_F + k] * W_e[k * (EF_F * H_HEADS) + h * EF_F + f];
        part += a_e[h * EF_F + f] * acc;
    }
    for (int off = 1; off < 8; off <<= 1)
        part += __shfl_xor(part, off, 64);
    if (fc == 0) s_e[t * H_HEADS + h] = part;
}

// ---------------- K1: fused GEMM  Z = h @ [W | res_W]  (fp32, 64x64 tile) ----------------
// by<4: emb cols (one head per tile) -> nan-guard, s_l/s_r epilogue, bf16 store
// by>=4: res cols -> +res_b, fp32 store to d_out
#define BM 64
#define BN 64
#define BK 16
__global__ __launch_bounds__(256)
void k_gemm(const float* __restrict__ A, const float* __restrict__ W,
            const float* __restrict__ resW, const float* __restrict__ resb,
            const float* __restrict__ a_l, const float* __restrict__ a_r,
            u16* __restrict__ emb_bf, float* __restrict__ s_l, float* __restrict__ s_r,
            float* __restrict__ outp) {
    __shared__ float At[BK][BM];   // k-major A tile
    __shared__ float Bt[BK][BN];
    const int tid = threadIdx.x;
    const int row0 = blockIdx.x * BM;
    const int by = blockIdx.y;               // 0..7
    const float* Bsrc = (by < 4) ? W : resW;
    const int bcol0 = (by & 3) * BN;

    const int tx = tid & 15;                 // col group (4 cols)
    const int ty = tid >> 4;                 // row group (4 rows)
    const int arow = tid >> 2;               // A-load row 0..63
    const int acol4 = (tid & 3) * 4;         // A-load k-offset
    const int brow = tid >> 4;               // B-load k 0..15
    const int bcol4 = (tid & 15) * 4;        // B-load col

    float acc[4][4] = {};
    for (int k0 = 0; k0 < IN_F; k0 += BK) {
        float4 av = make_float4(0.f, 0.f, 0.f, 0.f);
        if (row0 + arow < N_NODES)
            av = *reinterpret_cast<const float4*>(&A[(size_t)(row0 + arow) * IN_F + k0 + acol4]);
        float4 bv = *reinterpret_cast<const float4*>(&Bsrc[(size_t)(k0 + brow) * HD + bcol0 + bcol4]);
        __syncthreads();
        At[acol4 + 0][arow] = av.x;
        At[acol4 + 1][arow] = av.y;
        At[acol4 + 2][arow] = av.z;
        At[acol4 + 3][arow] = av.w;
        *reinterpret_cast<float4*>(&Bt[brow][bcol4]) = bv;
        __syncthreads();
#pragma unroll
        for (int k = 0; k < BK; ++k) {
            const float4 a = *reinterpret_cast<const float4*>(&At[k][ty * 4]);
            const float4 b = *reinterpret_cast<const float4*>(&Bt[k][tx * 4]);
            acc[0][0] += a.x * b.x; acc[0][1] += a.x * b.y; acc[0][2] += a.x * b.z; acc[0][3] += a.x * b.w;
            acc[1][0] += a.y * b.x; acc[1][1] += a.y * b.y; acc[1][2] += a.y * b.z; acc[1][3] += a.y * b.w;
            acc[2][0] += a.z * b.x; acc[2][1] += a.z * b.y; acc[2][2] += a.z * b.z; acc[2][3] += a.z * b.w;
            acc[3][0] += a.w * b.x; acc[3][1] += a.w * b.y; acc[3][2] += a.w * b.z; acc[3][3] += a.w * b.w;
        }
    }

    if (by < 4) {
        const int h = by;
#pragma unroll
        for (int r = 0; r < 4; ++r) {
            float dotl = 0.f, dotr = 0.f;
#pragma unroll
            for (int c = 0; c < 4; ++c) {
                float v = acc[r][c];
                v = isnan(v) ? 0.f : v;          // nan_to_num
                acc[r][c] = v;
                dotl += v * a_l[h * D_HEAD + tx * 4 + c];
                dotr += v * a_r[h * D_HEAD + tx * 4 + c];
            }
            for (int off = 1; off < 16; off <<= 1) {
                dotl += __shfl_xor(dotl, off, 64);
                dotr += __shfl_xor(dotr, off, 64);
            }
            const int node = row0 + ty * 4 + r;
            if (node < N_NODES) {
                if (tx == 0) {
                    s_l[node * H_HEADS + h] = dotl;
                    s_r[node * H_HEADS + h] = dotr;
                }
                u64 packed = (u64)f2bf(acc[r][0]) | ((u64)f2bf(acc[r][1]) << 16) |
                             ((u64)f2bf(acc[r][2]) << 32) | ((u64)f2bf(acc[r][3]) << 48);
                *reinterpret_cast<u64*>(&emb_bf[(size_t)node * HD + h * D_HEAD + tx * 4]) = packed;
            }
        }
    } else {
        const int c0 = (by - 4) * BN + tx * 4;
#pragma unroll
        for (int r = 0; r < 4; ++r) {
            const int node = row0 + ty * 4 + r;
            if (node < N_NODES) {
                float4 o;
                o.x = acc[r][0] + resb[c0 + 0];
                o.y = acc[r][1] + resb[c0 + 1];
                o.z = acc[r][2] + resb[c0 + 2];
                o.w = acc[r][3] + resb[c0 + 3];
                *reinterpret_cast<float4*>(&outp[(size_t)node * HD + c0]) = o;
            }
        }
    }
}

// ---------------- CSR build ----------------
__global__ void k_hist(const int* __restrict__ col, int* __restrict__ counts) {
    int e = blockIdx.x * 256 + threadIdx.x;
    if (e < E_EDGES) atomicAdd(&counts[col[e]], 1);
}

__global__ void k_scan1(const int* __restrict__ counts, int* __restrict__ row_ptr,
                        int* __restrict__ partials) {
    __shared__ int sd[256];
    const int t = threadIdx.x, b = blockIdx.x;
    const int base = b * 1024 + t * 4;
    int v[4];
#pragma unroll
    for (int j = 0; j < 4; ++j) v[j] = (base + j < N_NODES) ? counts[base + j] : 0;
    const int s = v[0] + v[1] + v[2] + v[3];
    sd[t] = s;
    __syncthreads();
    for (int off = 1; off < 256; off <<= 1) {
        int y = (t >= off) ? sd[t - off] : 0;
        __syncthreads();
        sd[t] += y;
        __syncthreads();
    }
    int p = sd[t] - s;   // exclusive prefix of this thread
#pragma unroll
    for (int j = 0; j < 4; ++j) {
        if (base + j < N_NODES) row_ptr[base + j] = p;
        p += v[j];
    }
    if (t == 255) partials[b] = sd[255];
}

__global__ void k_scan2(int* __restrict__ partials) {
    __shared__ int sd[128];
    const int t = threadIdx.x;
    const int v = (t < 98) ? partials[t] : 0;
    sd[t] = v;
    __syncthreads();
    for (int off = 1; off < 128; off <<= 1) {
        int y = (t >= off) ? sd[t - off] : 0;
        __syncthreads();
        sd[t] += y;
        __syncthreads();
    }
    if (t < 98) partials[t] = sd[t] - v;   // exclusive
}

__global__ void k_scan3(int* __restrict__ row_ptr, int* __restrict__ fill,
                        const int* __restrict__ partials) {
    const int i = blockIdx.x * 256 + threadIdx.x;
    if (i < N_NODES) {
        const int v = row_ptr[i] + partials[i >> 10];
        row_ptr[i] = v;
        fill[i] = v;
    }
    if (i == 0) row_ptr[N_NODES] = E_EDGES;
}

__global__ void k_scatter(const int* __restrict__ row, const int* __restrict__ col,
                          const int* __restrict__ tp, int* __restrict__ fill,
                          int* __restrict__ perm) {
    int e = blockIdx.x * 256 + threadIdx.x;
    if (e < E_EDGES) {
        int c = col[e];
        int p = atomicAdd(&fill[c], 1);
        perm[p] = row[e] | (tp[e] << 20);   // row < 2^17, tp < 8
    }
}

// ---------------- K5: per-destination aggregation (one wave per node) ----------------
__global__ __launch_bounds__(256)
void k_aggregate(const int* __restrict__ row_ptr, const int* __restrict__ perm,
                 const u16* __restrict__ emb_bf, const float* __restrict__ s_l,
                 const float* __restrict__ s_r, const float* __restrict__ s_e,
                 float* __restrict__ outp) {
    const int wave = threadIdx.x >> 6;
    const int lane = threadIdx.x & 63;
    const int n = blockIdx.x * 4 + wave;           // grid = N/4 exactly
    const int h = lane >> 4;                       // this lane's head
    const int start = row_ptr[n], end = row_ptr[n + 1];
    const float srh = s_r[n * H_HEADS + h];

    float a0 = 0.f, a1 = 0.f, a2 = 0.f, a3 = 0.f, den = 0.f;
    for (int i = start; i < end; ++i) {
        const int packed = perm[i];
        const int r = packed & 0xFFFFF;
        const int t = packed >> 20;
        float lg = s_l[r * H_HEADS + h] + srh + s_e[t * H_HEADS + h];
        lg = (lg > 0.f) ? lg : SLOPE * lg;
        const float ex = __expf(lg);
        const u64 ev = *reinterpret_cast<const u64*>(&emb_bf[(size_t)r * HD + lane * 4]);
        a0 += ex * bf2f((unsigned)(ev) & 0xFFFFu);
        a1 += ex * bf2f((unsigned)(ev >> 16) & 0xFFFFu);
        a2 += ex * bf2f((unsigned)(ev >> 32) & 0xFFFFu);
        a3 += ex * bf2f((unsigned)(ev >> 48) & 0xFFFFu);
        den += ex;
    }
    const float inv = (den > 0.f) ? 1.f / den : 0.f;
    const size_t o = (size_t)n * HD + lane * 4;
    float4 res = *reinterpret_cast<const float4*>(&outp[o]);
    float4 out;
    float x;
    x = a0 * inv + res.x; out.x = (x > 0.f) ? x : expm1f(x);
    x = a1 * inv + res.y; out.y = (x > 0.f) ? x : expm1f(x);
    x = a2 * inv + res.z; out.z = (x > 0.f) ? x : expm1f(x);
    x = a3 * inv + res.w; out.w = (x > 0.f) ? x : expm1f(x);
    *reinterpret_cast<float4*>(&outp[o]) = out;
}

extern "C" void kernel_launch(void* const* d_in, const int* in_sizes, int n_in,
                              void* d_out, int out_size, void* d_ws, size_t ws_size,
                              hipStream_t stream) {
    const float* h    = (const float*)d_in[0];
    const float* W    = (const float*)d_in[1];
    const float* W_e  = (const float*)d_in[2];
    const float* eemb = (const float*)d_in[3];
    const float* a_l  = (const float*)d_in[4];
    const float* a_r  = (const float*)d_in[5];
    const float* a_e  = (const float*)d_in[6];
    const float* resW = (const float*)d_in[7];
    const float* resb = (const float*)d_in[8];
    const int* row = (const int*)d_in[9];
    const int* col = (const int*)d_in[10];
    const int* tp  = (const int*)d_in[11];
    float* outp = (float*)d_out;

    char* ws = (char*)d_ws;
    size_t off = 0;
    auto alloc = [&](size_t b) { size_t o = off; off += (b + 255) & ~(size_t)255; return o; };
    u16*  emb_bf  = (u16*)(ws + alloc((size_t)N_NODES * HD * 2));
    float* s_l    = (float*)(ws + alloc((size_t)N_NODES * H_HEADS * 4));
    float* s_r    = (float*)(ws + alloc((size_t)N_NODES * H_HEADS * 4));
    float* s_e    = (float*)(ws + alloc(NET_T * H_HEADS * 4));
    int*  counts  = (int*)(ws + alloc((size_t)N_NODES * 4));
    int*  row_ptr = (int*)(ws + alloc((size_t)(N_NODES + 1) * 4));
    int*  fill    = (int*)(ws + alloc((size_t)N_NODES * 4));
    int*  perm    = (int*)(ws + alloc((size_t)E_EDGES * 4));
    int*  partials= (int*)(ws + alloc(128 * 4));

    k_se<<<1, 256, 0, stream>>>(eemb, W_e, a_e, s_e);
    dim3 g1((N_NODES + BM - 1) / BM, 8);
    k_gemm<<<g1, 256, 0, stream>>>(h, W, resW, resb, a_l, a_r, emb_bf, s_l, s_r, outp);
    hipMemsetAsync(counts, 0, (size_t)N_NODES * 4, stream);
    k_hist<<<(E_EDGES + 255) / 256, 256, 0, stream>>>(col, counts);
    k_scan1<<<98, 256, 0, stream>>>(counts, row_ptr, partials);
    k_scan2<<<1, 128, 0, stream>>>(partials);
    k_scan3<<<(N_NODES + 255) / 256, 256, 0, stream>>>(row_ptr, fill, partials);
    k_scatter<<<(E_EDGES + 255) / 256, 256, 0, stream>>>(row, col, tp, fill, perm);
    k_aggregate<<<N_NODES / 4, 256, 0, stream>>>(row_ptr, perm, emb_bf, s_l, s_r, s_e, outp);
}

// Round 2
// 419.448 us; speedup vs baseline: 1.5679x; 1.5679x over previous
//
#include <hip/hip_runtime.h>

#define N_NODES 100000
#define E_EDGES 800000
#define IN_F 256
#define D_HEAD 64
#define H_HEADS 4
#define EF_F 64
#define NET_T 8
#define HD 256          // H*D
#define SLOPE 0.2f

typedef unsigned short u16;
typedef unsigned long long u64;
typedef __attribute__((ext_vector_type(8))) short bf16x8;
typedef __attribute__((ext_vector_type(4))) float f32x4;

static __device__ __forceinline__ u16 f2bf(float f) {
    unsigned int u = __float_as_uint(f);
    unsigned int r = u + 0x7FFFu + ((u >> 16) & 1u);
    return (u16)(r >> 16);
}
static __device__ __forceinline__ float bf2f(unsigned int u) {
    return __uint_as_float(u << 16);
}

// ---------------- K0: s_e[t][h] = sum_f a_e[h,f] * (edge_emb @ W_e)[t,h,f] ----------------
__global__ void k_se(const float* __restrict__ edge_emb, const float* __restrict__ W_e,
                     const float* __restrict__ a_e, float* __restrict__ s_e) {
    int tid = threadIdx.x;           // 256 threads
    int t  = tid >> 5;               // 0..7
    int h  = (tid >> 3) & 3;         // 0..3
    int fc = tid & 7;                // 0..7
    float part = 0.f;
    for (int j = 0; j < 8; ++j) {
        int f = fc * 8 + j;
        float acc = 0.f;
        for (int k = 0; k < EF_F; ++k)
            acc += edge_emb[t * EF_F + k] * W_e[k * (EF_F * H_HEADS) + h * EF_F + f];
        part += a_e[h * EF_F + f] * acc;
    }
    for (int off = 1; off < 8; off <<= 1)
        part += __shfl_xor(part, off, 64);
    if (fc == 0) s_e[t * H_HEADS + h] = part;
}

// ---------------- K1a: h (fp32) -> h_bf (bf16) ----------------
__global__ void k_prep_h(const float* __restrict__ h, u16* __restrict__ hb) {
    const size_t i = ((size_t)blockIdx.x * 256 + threadIdx.x) * 8;
    float4 v0 = *reinterpret_cast<const float4*>(&h[i]);
    float4 v1 = *reinterpret_cast<const float4*>(&h[i + 4]);
    uint4 o;
    o.x = (unsigned)f2bf(v0.x) | ((unsigned)f2bf(v0.y) << 16);
    o.y = (unsigned)f2bf(v0.z) | ((unsigned)f2bf(v0.w) << 16);
    o.z = (unsigned)f2bf(v1.x) | ((unsigned)f2bf(v1.y) << 16);
    o.w = (unsigned)f2bf(v1.z) | ((unsigned)f2bf(v1.w) << 16);
    *reinterpret_cast<uint4*>(&hb[i]) = o;
}

// ---------------- K1b: Bt[n][k] = concat(W, res_W)[k][n] as bf16 ----------------
__global__ void k_prep_w(const float* __restrict__ W, const float* __restrict__ resW,
                         u16* __restrict__ Bt) {
    const int id = blockIdx.x * 256 + threadIdx.x;   // 512*256 total
    const int n = id >> 8;
    const int k = id & 255;
    const float v = (n < HD) ? W[k * HD + n] : resW[k * HD + (n - HD)];
    Bt[id] = f2bf(v);
}

// ---------------- K2: MFMA GEMM  Z = h_bf @ Bt^T  (bf16 in, fp32 acc) ----------------
// grid (ceil(N/64), 2), 256 threads = 4 waves. Global col-wave wid = by*4+w in 0..7.
// wid<4: emb head wid -> nan-guard, s_l/s_r epilogue, bf16 store.
// wid>=4: residual cols -> +res_b, fp32 store to d_out.
__global__ __launch_bounds__(256)
void k_mfma(const u16* __restrict__ Abf, const u16* __restrict__ Bt,
            const float* __restrict__ a_l, const float* __restrict__ a_r,
            const float* __restrict__ resb,
            u16* __restrict__ emb_bf, float* __restrict__ s_l, float* __restrict__ s_r,
            float* __restrict__ outp) {
    const int lane = threadIdx.x & 63;
    const int wid = (blockIdx.y << 2) | (threadIdx.x >> 6);   // 0..7
    const int row0 = blockIdx.x * 64;
    const int n0 = wid * 64;                                  // 0..511
    const int lr = lane & 15;
    const int lg = lane >> 4;

    int ar[4];
#pragma unroll
    for (int m = 0; m < 4; ++m) {
        int r = row0 + m * 16 + lr;
        ar[m] = (r < N_NODES) ? r : (N_NODES - 1);
    }

    f32x4 acc[4][4] = {};
#pragma unroll
    for (int ks = 0; ks < 8; ++ks) {
        const int koff = ks * 32 + lg * 8;
        bf16x8 af[4], bf[4];
#pragma unroll
        for (int m = 0; m < 4; ++m)
            af[m] = *reinterpret_cast<const bf16x8*>(&Abf[(size_t)ar[m] * IN_F + koff]);
#pragma unroll
        for (int n = 0; n < 4; ++n)
            bf[n] = *reinterpret_cast<const bf16x8*>(&Bt[(size_t)(n0 + n * 16 + lr) * IN_F + koff]);
#pragma unroll
        for (int m = 0; m < 4; ++m)
#pragma unroll
            for (int n = 0; n < 4; ++n)
                acc[m][n] = __builtin_amdgcn_mfma_f32_16x16x32_bf16(af[m], bf[n], acc[m][n], 0, 0, 0);
    }

    if (wid < 4) {
        const int h = wid;
        float alv[4], arv[4];
#pragma unroll
        for (int n = 0; n < 4; ++n) {
            alv[n] = a_l[h * D_HEAD + n * 16 + lr];
            arv[n] = a_r[h * D_HEAD + n * 16 + lr];
        }
#pragma unroll
        for (int m = 0; m < 4; ++m) {
#pragma unroll
            for (int r = 0; r < 4; ++r) {
                const int node = row0 + m * 16 + lg * 4 + r;
                float dl = 0.f, dr = 0.f;
                u16 pk[4];
#pragma unroll
                for (int n = 0; n < 4; ++n) {
                    float v = acc[m][n][r];
                    v = isnan(v) ? 0.f : v;      // nan_to_num
                    dl += v * alv[n];
                    dr += v * arv[n];
                    pk[n] = f2bf(v);
                }
                if (node < N_NODES) {
                    const size_t base = (size_t)node * HD + h * D_HEAD;
#pragma unroll
                    for (int n = 0; n < 4; ++n)
                        emb_bf[base + n * 16 + lr] = pk[n];
                }
                dl += __shfl_xor(dl, 1, 64); dr += __shfl_xor(dr, 1, 64);
                dl += __shfl_xor(dl, 2, 64); dr += __shfl_xor(dr, 2, 64);
                dl += __shfl_xor(dl, 4, 64); dr += __shfl_xor(dr, 4, 64);
                dl += __shfl_xor(dl, 8, 64); dr += __shfl_xor(dr, 8, 64);
                if (lr == 0 && node < N_NODES) {
                    s_l[node * H_HEADS + h] = dl;
                    s_r[node * H_HEADS + h] = dr;
                }
            }
        }
    } else {
        const int c0 = (wid - 4) * 64;
        float rb[4];
#pragma unroll
        for (int n = 0; n < 4; ++n) rb[n] = resb[c0 + n * 16 + lr];
#pragma unroll
        for (int m = 0; m < 4; ++m) {
#pragma unroll
            for (int r = 0; r < 4; ++r) {
                const int node = row0 + m * 16 + lg * 4 + r;
                if (node < N_NODES) {
                    const size_t base = (size_t)node * HD + c0;
#pragma unroll
                    for (int n = 0; n < 4; ++n)
                        outp[base + n * 16 + lr] = acc[m][n][r] + rb[n];
                }
            }
        }
    }
}

// ---------------- CSR build ----------------
__global__ void k_hist(const int* __restrict__ col, int* __restrict__ counts) {
    int e = blockIdx.x * 256 + threadIdx.x;
    if (e < E_EDGES) atomicAdd(&counts[col[e]], 1);
}

__global__ void k_scan1(const int* __restrict__ counts, int* __restrict__ row_ptr,
                        int* __restrict__ partials) {
    __shared__ int sd[256];
    const int t = threadIdx.x, b = blockIdx.x;
    const int base = b * 1024 + t * 4;
    int v[4];
#pragma unroll
    for (int j = 0; j < 4; ++j) v[j] = (base + j < N_NODES) ? counts[base + j] : 0;
    const int s = v[0] + v[1] + v[2] + v[3];
    sd[t] = s;
    __syncthreads();
    for (int off = 1; off < 256; off <<= 1) {
        int y = (t >= off) ? sd[t - off] : 0;
        __syncthreads();
        sd[t] += y;
        __syncthreads();
    }
    int p = sd[t] - s;
#pragma unroll
    for (int j = 0; j < 4; ++j) {
        if (base + j < N_NODES) row_ptr[base + j] = p;
        p += v[j];
    }
    if (t == 255) partials[b] = sd[255];
}

__global__ void k_scan2(int* __restrict__ partials) {
    __shared__ int sd[128];
    const int t = threadIdx.x;
    const int v = (t < 98) ? partials[t] : 0;
    sd[t] = v;
    __syncthreads();
    for (int off = 1; off < 128; off <<= 1) {
        int y = (t >= off) ? sd[t - off] : 0;
        __syncthreads();
        sd[t] += y;
        __syncthreads();
    }
    if (t < 98) partials[t] = sd[t] - v;
}

__global__ void k_scan3(int* __restrict__ row_ptr, int* __restrict__ fill,
                        const int* __restrict__ partials) {
    const int i = blockIdx.x * 256 + threadIdx.x;
    if (i < N_NODES) {
        const int v = row_ptr[i] + partials[i >> 10];
        row_ptr[i] = v;
        fill[i] = v;
    }
    if (i == 0) row_ptr[N_NODES] = E_EDGES;
}

__global__ void k_scatter(const int* __restrict__ row, const int* __restrict__ col,
                          const int* __restrict__ tp, int* __restrict__ fill,
                          int* __restrict__ perm) {
    int e = blockIdx.x * 256 + threadIdx.x;
    if (e < E_EDGES) {
        int c = col[e];
        int p = atomicAdd(&fill[c], 1);
        perm[p] = row[e] | (tp[e] << 20);   // row < 2^17, tp < 8
    }
}

// ---------------- K5: per-destination aggregation (one wave per node) ----------------
__global__ __launch_bounds__(256)
void k_aggregate(const int* __restrict__ row_ptr, const int* __restrict__ perm,
                 const u16* __restrict__ emb_bf, const float* __restrict__ s_l,
                 const float* __restrict__ s_r, const float* __restrict__ s_e,
                 float* __restrict__ outp) {
    const int wave = threadIdx.x >> 6;
    const int lane = threadIdx.x & 63;
    const int n = blockIdx.x * 4 + wave;           // grid = N/4 exactly
    const int h = lane >> 4;                       // this lane's head
    const int start = row_ptr[n], end = row_ptr[n + 1];
    const float srh = s_r[n * H_HEADS + h];

    float a0 = 0.f, a1 = 0.f, a2 = 0.f, a3 = 0.f, den = 0.f;
    for (int i = start; i < end; ++i) {
        const int packed = perm[i];
        const int r = packed & 0xFFFFF;
        const int t = packed >> 20;
        float lg = s_l[r * H_HEADS + h] + srh + s_e[t * H_HEADS + h];
        lg = (lg > 0.f) ? lg : SLOPE * lg;
        const float ex = __expf(lg);
        const u64 ev = *reinterpret_cast<const u64*>(&emb_bf[(size_t)r * HD + lane * 4]);
        a0 += ex * bf2f((unsigned)(ev) & 0xFFFFu);
        a1 += ex * bf2f((unsigned)(ev >> 16) & 0xFFFFu);
        a2 += ex * bf2f((unsigned)(ev >> 32) & 0xFFFFu);
        a3 += ex * bf2f((unsigned)(ev >> 48) & 0xFFFFu);
        den += ex;
    }
    const float inv = (den > 0.f) ? 1.f / den : 0.f;
    const size_t o = (size_t)n * HD + lane * 4;
    float4 res = *reinterpret_cast<const float4*>(&outp[o]);
    float4 out;
    float x;
    x = a0 * inv + res.x; out.x = (x > 0.f) ? x : expm1f(x);
    x = a1 * inv + res.y; out.y = (x > 0.f) ? x : expm1f(x);
    x = a2 * inv + res.z; out.z = (x > 0.f) ? x : expm1f(x);
    x = a3 * inv + res.w; out.w = (x > 0.f) ? x : expm1f(x);
    *reinterpret_cast<float4*>(&outp[o]) = out;
}

extern "C" void kernel_launch(void* const* d_in, const int* in_sizes, int n_in,
                              void* d_out, int out_size, void* d_ws, size_t ws_size,
                              hipStream_t stream) {
    const float* h    = (const float*)d_in[0];
    const float* W    = (const float*)d_in[1];
    const float* W_e  = (const float*)d_in[2];
    const float* eemb = (const float*)d_in[3];
    const float* a_l  = (const float*)d_in[4];
    const float* a_r  = (const float*)d_in[5];
    const float* a_e  = (const float*)d_in[6];
    const float* resW = (const float*)d_in[7];
    const float* resb = (const float*)d_in[8];
    const int* row = (const int*)d_in[9];
    const int* col = (const int*)d_in[10];
    const int* tp  = (const int*)d_in[11];
    float* outp = (float*)d_out;

    char* ws = (char*)d_ws;
    size_t off = 0;
    auto alloc = [&](size_t b) { size_t o = off; off += (b + 255) & ~(size_t)255; return o; };
    u16*  h_bf    = (u16*)(ws + alloc((size_t)N_NODES * IN_F * 2));
    u16*  Bt      = (u16*)(ws + alloc((size_t)512 * IN_F * 2));
    u16*  emb_bf  = (u16*)(ws + alloc((size_t)N_NODES * HD * 2));
    float* s_l    = (float*)(ws + alloc((size_t)N_NODES * H_HEADS * 4));
    float* s_r    = (float*)(ws + alloc((size_t)N_NODES * H_HEADS * 4));
    float* s_e    = (float*)(ws + alloc(NET_T * H_HEADS * 4));
    int*  counts  = (int*)(ws + alloc((size_t)N_NODES * 4));
    int*  row_ptr = (int*)(ws + alloc((size_t)(N_NODES + 1) * 4));
    int*  fill    = (int*)(ws + alloc((size_t)N_NODES * 4));
    int*  perm    = (int*)(ws + alloc((size_t)E_EDGES * 4));
    int*  partials= (int*)(ws + alloc(128 * 4));

    k_se<<<1, 256, 0, stream>>>(eemb, W_e, a_e, s_e);
    k_prep_h<<<(N_NODES * IN_F) / (256 * 8), 256, 0, stream>>>(h, h_bf);
    k_prep_w<<<512, 256, 0, stream>>>(W, resW, Bt);
    dim3 g2((N_NODES + 63) / 64, 2);
    k_mfma<<<g2, 256, 0, stream>>>(h_bf, Bt, a_l, a_r, resb, emb_bf, s_l, s_r, outp);
    hipMemsetAsync(counts, 0, (size_t)N_NODES * 4, stream);
    k_hist<<<(E_EDGES + 255) / 256, 256, 0, stream>>>(col, counts);
    k_scan1<<<98, 256, 0, stream>>>(counts, row_ptr, partials);
    k_scan2<<<1, 128, 0, stream>>>(partials);
    k_scan3<<<(N_NODES + 255) / 256, 256, 0, stream>>>(row_ptr, fill, partials);
    k_scatter<<<(E_EDGES + 255) / 256, 256, 0, stream>>>(row, col, tp, fill, perm);
    k_aggregate<<<N_NODES / 4, 256, 0, stream>>>(row_ptr, perm, emb_bf, s_l, s_r, s_e, outp);
}

// Round 3
// 343.074 us; speedup vs baseline: 1.9169x; 1.2226x over previous
//
#include <hip/hip_runtime.h>

#define N_NODES 100000
#define E_EDGES 800000
#define IN_F 256
#define D_HEAD 64
#define H_HEADS 4
#define EF_F 64
#define NET_T 8
#define HD 256          // H*D
#define SLOPE 0.2f

typedef unsigned short u16;
typedef unsigned long long u64;
typedef __attribute__((ext_vector_type(8))) short bf16x8;
typedef __attribute__((ext_vector_type(4))) float f32x4;

static __device__ __forceinline__ u16 f2bf(float f) {
    unsigned int u = __float_as_uint(f);
    unsigned int r = u + 0x7FFFu + ((u >> 16) & 1u);
    return (u16)(r >> 16);
}
static __device__ __forceinline__ float bf2f(unsigned int u) {
    return __uint_as_float(u << 16);
}

// ---------------- K0: s_e[t][h] = sum_f a_e[h,f] * (edge_emb @ W_e)[t,h,f] ----------------
__global__ void k_se(const float* __restrict__ edge_emb, const float* __restrict__ W_e,
                     const float* __restrict__ a_e, float* __restrict__ s_e) {
    int tid = threadIdx.x;           // 256 threads
    int t  = tid >> 5;               // 0..7
    int h  = (tid >> 3) & 3;         // 0..3
    int fc = tid & 7;                // 0..7
    float part = 0.f;
    for (int j = 0; j < 8; ++j) {
        int f = fc * 8 + j;
        float acc = 0.f;
        for (int k = 0; k < EF_F; ++k)
            acc += edge_emb[t * EF_F + k] * W_e[k * (EF_F * H_HEADS) + h * EF_F + f];
        part += a_e[h * EF_F + f] * acc;
    }
    for (int off = 1; off < 8; off <<= 1)
        part += __shfl_xor(part, off, 64);
    if (fc == 0) s_e[t * H_HEADS + h] = part;
}

// ---------------- K1: Bt[n][k] = concat(W, res_W)[k][n] as bf16 ----------------
__global__ void k_prep_w(const float* __restrict__ W, const float* __restrict__ resW,
                         u16* __restrict__ Bt) {
    const int id = blockIdx.x * 256 + threadIdx.x;   // 512*256 total
    const int n = id >> 8;
    const int k = id & 255;
    const float v = (n < HD) ? W[k * HD + n] : resW[k * HD + (n - HD)];
    Bt[id] = f2bf(v);
}

// ---------------- K2: fused convert + MFMA GEMM  Z = bf16(h) @ Bt^T ----------------
// 512 threads = 8 waves; block covers 64 rows x all 512 cols. A-tile staged to LDS
// once (fp32->bf16 convert in flight, XOR-swizzled to kill ds_read bank conflicts).
// wid<4: emb head wid -> nan-guard, s_l/s_r epilogue, bf16 store.
// wid>=4: residual cols -> +res_b, fp32 store to d_out.
__global__ __launch_bounds__(512, 2)
void k_mfma(const float* __restrict__ A, const u16* __restrict__ Bt,
            const float* __restrict__ a_l, const float* __restrict__ a_r,
            const float* __restrict__ resb,
            u16* __restrict__ emb_bf, float* __restrict__ s_l, float* __restrict__ s_r,
            float* __restrict__ outp) {
    __shared__ char At[32768];       // 64 rows x 256 bf16, XOR-swizzled
    const int tid = threadIdx.x;
    const int lane = tid & 63;
    const int wid = tid >> 6;        // 0..7 = column-group
    const int row0 = blockIdx.x * 64;

    // ---- stage: 8 iters x 512 thr x 8B(bf16) = 32KB; fp32 read 16B/thread ----
#pragma unroll
    for (int c = 0; c < 8; ++c) {
        const int lin8 = c * 4096 + tid * 8;          // linear byte in bf16 tile
        const int r_lin = lin8 >> 9;                  // tile row 0..63
        int grow = row0 + r_lin;
        if (grow >= N_NODES) grow = N_NODES - 1;      // clamp (stores masked later)
        const int colb = lin8 & 511;                  // byte col within bf16 row
        const float4 v = *reinterpret_cast<const float4*>(&A[(size_t)grow * IN_F + (colb >> 1)]);
        uint2 o;
        o.x = (unsigned)f2bf(v.x) | ((unsigned)f2bf(v.y) << 16);
        o.y = (unsigned)f2bf(v.z) | ((unsigned)f2bf(v.w) << 16);
        *reinterpret_cast<uint2*>(&At[lin8 ^ ((r_lin & 7) << 4)]) = o;
    }
    __syncthreads();

    const int lr = lane & 15;
    const int lg = lane >> 4;
    const int xr = (lr & 7) << 4;                     // swizzle term (row&7 == lr&7)
    const int klg = lg * 16;
    const int n0 = wid * 64;

    int rowbase[4];
#pragma unroll
    for (int m = 0; m < 4; ++m) rowbase[m] = (m * 16 + lr) * 512;

    f32x4 acc[4][4] = {};
#pragma unroll
    for (int ks = 0; ks < 8; ++ks) {
        const int koff = ks * 32 + klg / 2;           // u16 index into B row
        bf16x8 af[4], bfr[4];
        const int kx = ((ks << 6) + klg) ^ xr;        // swizzled intra-row byte
#pragma unroll
        for (int m = 0; m < 4; ++m)
            af[m] = *reinterpret_cast<const bf16x8*>(&At[rowbase[m] + kx]);
#pragma unroll
        for (int n = 0; n < 4; ++n)
            bfr[n] = *reinterpret_cast<const bf16x8*>(&Bt[(size_t)(n0 + n * 16 + lr) * IN_F + koff]);
#pragma unroll
        for (int m = 0; m < 4; ++m)
#pragma unroll
            for (int n = 0; n < 4; ++n)
                acc[m][n] = __builtin_amdgcn_mfma_f32_16x16x32_bf16(af[m], bfr[n], acc[m][n], 0, 0, 0);
    }

    if (wid < 4) {
        const int h = wid;
        float alv[4], arv[4];
#pragma unroll
        for (int n = 0; n < 4; ++n) {
            alv[n] = a_l[h * D_HEAD + n * 16 + lr];
            arv[n] = a_r[h * D_HEAD + n * 16 + lr];
        }
#pragma unroll
        for (int m = 0; m < 4; ++m) {
#pragma unroll
            for (int r = 0; r < 4; ++r) {
                const int node = row0 + m * 16 + lg * 4 + r;
                float dl = 0.f, dr = 0.f;
                u16 pk[4];
#pragma unroll
                for (int n = 0; n < 4; ++n) {
                    float v = acc[m][n][r];
                    v = isnan(v) ? 0.f : v;      // nan_to_num
                    dl += v * alv[n];
                    dr += v * arv[n];
                    pk[n] = f2bf(v);
                }
                if (node < N_NODES) {
                    const size_t base = (size_t)node * HD + h * D_HEAD;
#pragma unroll
                    for (int n = 0; n < 4; ++n)
                        emb_bf[base + n * 16 + lr] = pk[n];
                }
                dl += __shfl_xor(dl, 1, 64); dr += __shfl_xor(dr, 1, 64);
                dl += __shfl_xor(dl, 2, 64); dr += __shfl_xor(dr, 2, 64);
                dl += __shfl_xor(dl, 4, 64); dr += __shfl_xor(dr, 4, 64);
                dl += __shfl_xor(dl, 8, 64); dr += __shfl_xor(dr, 8, 64);
                if (lr == 0 && node < N_NODES) {
                    s_l[node * H_HEADS + h] = dl;
                    s_r[node * H_HEADS + h] = dr;
                }
            }
        }
    } else {
        const int c0 = (wid - 4) * 64;
        float rb[4];
#pragma unroll
        for (int n = 0; n < 4; ++n) rb[n] = resb[c0 + n * 16 + lr];
#pragma unroll
        for (int m = 0; m < 4; ++m) {
#pragma unroll
            for (int r = 0; r < 4; ++r) {
                const int node = row0 + m * 16 + lg * 4 + r;
                if (node < N_NODES) {
                    const size_t base = (size_t)node * HD + c0;
#pragma unroll
                    for (int n = 0; n < 4; ++n)
                        outp[base + n * 16 + lr] = acc[m][n][r] + rb[n];
                }
            }
        }
    }
}

// ---------------- CSR build ----------------
__global__ void k_hist(const int* __restrict__ col, int* __restrict__ counts) {
    int e = blockIdx.x * 256 + threadIdx.x;
    if (e < E_EDGES) atomicAdd(&counts[col[e]], 1);
}

__global__ void k_scan1(const int* __restrict__ counts, int* __restrict__ row_ptr,
                        int* __restrict__ partials) {
    __shared__ int sd[256];
    const int t = threadIdx.x, b = blockIdx.x;
    const int base = b * 1024 + t * 4;
    int v[4];
#pragma unroll
    for (int j = 0; j < 4; ++j) v[j] = (base + j < N_NODES) ? counts[base + j] : 0;
    const int s = v[0] + v[1] + v[2] + v[3];
    sd[t] = s;
    __syncthreads();
    for (int off = 1; off < 256; off <<= 1) {
        int y = (t >= off) ? sd[t - off] : 0;
        __syncthreads();
        sd[t] += y;
        __syncthreads();
    }
    int p = sd[t] - s;
#pragma unroll
    for (int j = 0; j < 4; ++j) {
        if (base + j < N_NODES) row_ptr[base + j] = p;
        p += v[j];
    }
    if (t == 255) partials[b] = sd[255];
}

__global__ void k_scan2(int* __restrict__ partials) {
    __shared__ int sd[128];
    const int t = threadIdx.x;
    const int v = (t < 98) ? partials[t] : 0;
    sd[t] = v;
    __syncthreads();
    for (int off = 1; off < 128; off <<= 1) {
        int y = (t >= off) ? sd[t - off] : 0;
        __syncthreads();
        sd[t] += y;
        __syncthreads();
    }
    if (t < 98) partials[t] = sd[t] - v;
}

__global__ void k_scan3(int* __restrict__ row_ptr, int* __restrict__ fill,
                        const int* __restrict__ partials) {
    const int i = blockIdx.x * 256 + threadIdx.x;
    if (i < N_NODES) {
        const int v = row_ptr[i] + partials[i >> 10];
        row_ptr[i] = v;
        fill[i] = v;
    }
    if (i == 0) row_ptr[N_NODES] = E_EDGES;
}

__global__ void k_scatter(const int* __restrict__ row, const int* __restrict__ col,
                          const int* __restrict__ tp, int* __restrict__ fill,
                          int* __restrict__ perm) {
    int e = blockIdx.x * 256 + threadIdx.x;
    if (e < E_EDGES) {
        int c = col[e];
        int p = atomicAdd(&fill[c], 1);
        perm[p] = row[e] | (tp[e] << 20);   // row < 2^17, tp < 8
    }
}

// ---------------- K5: per-destination aggregation (one wave per node) ----------------
__global__ __launch_bounds__(256)
void k_aggregate(const int* __restrict__ row_ptr, const int* __restrict__ perm,
                 const u16* __restrict__ emb_bf, const float* __restrict__ s_l,
                 const float* __restrict__ s_r, const float* __restrict__ s_e,
                 float* __restrict__ outp) {
    const int wave = threadIdx.x >> 6;
    const int lane = threadIdx.x & 63;
    const int n = blockIdx.x * 4 + wave;           // grid = N/4 exactly
    const int h = lane >> 4;                       // this lane's head
    const int start = row_ptr[n], end = row_ptr[n + 1];
    const float srh = s_r[n * H_HEADS + h];

    float se_h[NET_T];
#pragma unroll
    for (int t = 0; t < NET_T; ++t) se_h[t] = s_e[t * H_HEADS + h];

    float a0 = 0.f, a1 = 0.f, a2 = 0.f, a3 = 0.f, den = 0.f;
    int i = start;
    // 2-wide pipeline: both gathers in flight before either use
    for (; i + 2 <= end; i += 2) {
        const int p0 = perm[i], p1 = perm[i + 1];
        const int r0 = p0 & 0xFFFFF, r1 = p1 & 0xFFFFF;
        const u64 ev0 = *reinterpret_cast<const u64*>(&emb_bf[(size_t)r0 * HD + lane * 4]);
        const u64 ev1 = *reinterpret_cast<const u64*>(&emb_bf[(size_t)r1 * HD + lane * 4]);
        const float sl0 = s_l[r0 * H_HEADS + h];
        const float sl1 = s_l[r1 * H_HEADS + h];
        float lg0 = sl0 + srh + se_h[p0 >> 20];
        float lg1 = sl1 + srh + se_h[p1 >> 20];
        lg0 = (lg0 > 0.f) ? lg0 : SLOPE * lg0;
        lg1 = (lg1 > 0.f) ? lg1 : SLOPE * lg1;
        const float ex0 = __expf(lg0);
        const float ex1 = __expf(lg1);
        a0 += ex0 * bf2f((unsigned)(ev0) & 0xFFFFu)      + ex1 * bf2f((unsigned)(ev1) & 0xFFFFu);
        a1 += ex0 * bf2f((unsigned)(ev0 >> 16) & 0xFFFFu) + ex1 * bf2f((unsigned)(ev1 >> 16) & 0xFFFFu);
        a2 += ex0 * bf2f((unsigned)(ev0 >> 32) & 0xFFFFu) + ex1 * bf2f((unsigned)(ev1 >> 32) & 0xFFFFu);
        a3 += ex0 * bf2f((unsigned)(ev0 >> 48) & 0xFFFFu) + ex1 * bf2f((unsigned)(ev1 >> 48) & 0xFFFFu);
        den += ex0 + ex1;
    }
    if (i < end) {
        const int p0 = perm[i];
        const int r0 = p0 & 0xFFFFF;
        const u64 ev0 = *reinterpret_cast<const u64*>(&emb_bf[(size_t)r0 * HD + lane * 4]);
        float lg0 = s_l[r0 * H_HEADS + h] + srh + se_h[p0 >> 20];
        lg0 = (lg0 > 0.f) ? lg0 : SLOPE * lg0;
        const float ex0 = __expf(lg0);
        a0 += ex0 * bf2f((unsigned)(ev0) & 0xFFFFu);
        a1 += ex0 * bf2f((unsigned)(ev0 >> 16) & 0xFFFFu);
        a2 += ex0 * bf2f((unsigned)(ev0 >> 32) & 0xFFFFu);
        a3 += ex0 * bf2f((unsigned)(ev0 >> 48) & 0xFFFFu);
        den += ex0;
    }
    const float inv = (den > 0.f) ? 1.f / den : 0.f;
    const size_t o = (size_t)n * HD + lane * 4;
    float4 res = *reinterpret_cast<const float4*>(&outp[o]);
    float4 out;
    float x;
    x = a0 * inv + res.x; out.x = (x > 0.f) ? x : expm1f(x);
    x = a1 * inv + res.y; out.y = (x > 0.f) ? x : expm1f(x);
    x = a2 * inv + res.z; out.z = (x > 0.f) ? x : expm1f(x);
    x = a3 * inv + res.w; out.w = (x > 0.f) ? x : expm1f(x);
    *reinterpret_cast<float4*>(&outp[o]) = out;
}

extern "C" void kernel_launch(void* const* d_in, const int* in_sizes, int n_in,
                              void* d_out, int out_size, void* d_ws, size_t ws_size,
                              hipStream_t stream) {
    const float* h    = (const float*)d_in[0];
    const float* W    = (const float*)d_in[1];
    const float* W_e  = (const float*)d_in[2];
    const float* eemb = (const float*)d_in[3];
    const float* a_l  = (const float*)d_in[4];
    const float* a_r  = (const float*)d_in[5];
    const float* a_e  = (const float*)d_in[6];
    const float* resW = (const float*)d_in[7];
    const float* resb = (const float*)d_in[8];
    const int* row = (const int*)d_in[9];
    const int* col = (const int*)d_in[10];
    const int* tp  = (const int*)d_in[11];
    float* outp = (float*)d_out;

    char* ws = (char*)d_ws;
    size_t off = 0;
    auto alloc = [&](size_t b) { size_t o = off; off += (b + 255) & ~(size_t)255; return o; };
    u16*  Bt      = (u16*)(ws + alloc((size_t)512 * IN_F * 2));
    u16*  emb_bf  = (u16*)(ws + alloc((size_t)N_NODES * HD * 2));
    float* s_l    = (float*)(ws + alloc((size_t)N_NODES * H_HEADS * 4));
    float* s_r    = (float*)(ws + alloc((size_t)N_NODES * H_HEADS * 4));
    float* s_e    = (float*)(ws + alloc(NET_T * H_HEADS * 4));
    int*  counts  = (int*)(ws + alloc((size_t)N_NODES * 4));
    int*  row_ptr = (int*)(ws + alloc((size_t)(N_NODES + 1) * 4));
    int*  fill    = (int*)(ws + alloc((size_t)N_NODES * 4));
    int*  perm    = (int*)(ws + alloc((size_t)E_EDGES * 4));
    int*  partials= (int*)(ws + alloc(128 * 4));

    k_se<<<1, 256, 0, stream>>>(eemb, W_e, a_e, s_e);
    k_prep_w<<<512, 256, 0, stream>>>(W, resW, Bt);
    k_mfma<<<(N_NODES + 63) / 64, 512, 0, stream>>>(h, Bt, a_l, a_r, resb, emb_bf, s_l, s_r, outp);
    hipMemsetAsync(counts, 0, (size_t)N_NODES * 4, stream);
    k_hist<<<(E_EDGES + 255) / 256, 256, 0, stream>>>(col, counts);
    k_scan1<<<98, 256, 0, stream>>>(counts, row_ptr, partials);
    k_scan2<<<1, 128, 0, stream>>>(partials);
    k_scan3<<<(N_NODES + 255) / 256, 256, 0, stream>>>(row_ptr, fill, partials);
    k_scatter<<<(E_EDGES + 255) / 256, 256, 0, stream>>>(row, col, tp, fill, perm);
    k_aggregate<<<N_NODES / 4, 256, 0, stream>>>(row_ptr, perm, emb_bf, s_l, s_r, s_e, outp);
}

// Round 4
// 322.616 us; speedup vs baseline: 2.0385x; 1.0634x over previous
//
#include <hip/hip_runtime.h>

#define N_NODES 100000
#define E_EDGES 800000
#define IN_F 256
#define D_HEAD 64
#define H_HEADS 4
#define EF_F 64
#define NET_T 8
#define HD 256          // H*D
#define SLOPE 0.2f

typedef unsigned short u16;
typedef unsigned long long u64;
typedef __attribute__((ext_vector_type(8))) short bf16x8;
typedef __attribute__((ext_vector_type(4))) float f32x4;

static __device__ __forceinline__ u16 f2bf(float f) {
    unsigned int u = __float_as_uint(f);
    unsigned int r = u + 0x7FFFu + ((u >> 16) & 1u);
    return (u16)(r >> 16);
}
static __device__ __forceinline__ float bf2f(unsigned int u) {
    return __uint_as_float(u << 16);
}

// ---------------- K0: s_e[t][h] = sum_f a_e[h,f] * (edge_emb @ W_e)[t,h,f] ----------------
__global__ void k_se(const float* __restrict__ edge_emb, const float* __restrict__ W_e,
                     const float* __restrict__ a_e, float* __restrict__ s_e) {
    int tid = threadIdx.x;           // 256 threads
    int t  = tid >> 5;               // 0..7
    int h  = (tid >> 3) & 3;         // 0..3
    int fc = tid & 7;                // 0..7
    float part = 0.f;
    for (int j = 0; j < 8; ++j) {
        int f = fc * 8 + j;
        float acc = 0.f;
        for (int k = 0; k < EF_F; ++k)
            acc += edge_emb[t * EF_F + k] * W_e[k * (EF_F * H_HEADS) + h * EF_F + f];
        part += a_e[h * EF_F + f] * acc;
    }
    for (int off = 1; off < 8; off <<= 1)
        part += __shfl_xor(part, off, 64);
    if (fc == 0) s_e[t * H_HEADS + h] = part;
}

// ---------------- K1: Bfrag[g][ks][n][lane] fragment-major bf16 of [W | res_W]^T ----------
// frag (g,ks,n), lane: ch = g*64 + n*16 + (lane&15); k = ks*32 + (lane>>4)*8 + j (j=0..7)
__global__ void k_prep_w(const float* __restrict__ W, const float* __restrict__ resW,
                         u16* __restrict__ Bfrag) {
    const int gid = blockIdx.x * 256 + threadIdx.x;   // 16384 total
    const int lane = gid & 63;
    const int fragid = gid >> 6;          // 0..255 = g*32 + ks*4 + n
    const int n = fragid & 3;
    const int ks = (fragid >> 2) & 7;
    const int g = fragid >> 5;            // 0..7
    const int c = g * 64 + n * 16 + (lane & 15);      // 0..511
    const int k0 = ks * 32 + (lane >> 4) * 8;
    const float* src = (c < HD) ? &W[c] : &resW[c - HD];
    u16 tmp[8];
#pragma unroll
    for (int j = 0; j < 8; ++j)
        tmp[j] = f2bf(src[(size_t)(k0 + j) * HD]);
    *reinterpret_cast<uint4*>(&Bfrag[(size_t)fragid * 512 + lane * 8]) =
        *reinterpret_cast<const uint4*>(tmp);
}

// ---------------- K2: fused convert + MFMA GEMM (operand-swapped, D[ch][node]) ------------
// 512 thr = 8 waves; A-tile (64 rows x 256) staged to LDS once, XOR-swizzled.
// acc[m][n] = mfma(B-chs-frag, A-node-frag): lane holds 4 consecutive channels per frag.
// wid<4: emb head wid -> nan-guard, dot4 s_l/s_r (2 shuffles), u64 bf16 stores.
// wid>=4: residual cols -> +res_b, float4 stores to d_out.
__global__ __launch_bounds__(512, 2)
void k_mfma(const float* __restrict__ A, const u16* __restrict__ Bfrag,
            const float* __restrict__ a_l, const float* __restrict__ a_r,
            const float* __restrict__ resb,
            u16* __restrict__ emb_bf, float* __restrict__ s_l, float* __restrict__ s_r,
            float* __restrict__ outp) {
    __shared__ char At[32768];       // 64 rows x 256 bf16, XOR-swizzled
    const int tid = threadIdx.x;
    const int lane = tid & 63;
    const int wid = tid >> 6;        // 0..7 = channel-group
    const int row0 = blockIdx.x * 64;

    // ---- stage: 8 iters x 512 thr x 8B(bf16); fp32 read 16B/thread ----
#pragma unroll
    for (int c = 0; c < 8; ++c) {
        const int lin8 = c * 4096 + tid * 8;          // linear byte in bf16 tile
        const int r_lin = lin8 >> 9;                  // tile row 0..63
        int grow = row0 + r_lin;
        if (grow >= N_NODES) grow = N_NODES - 1;      // clamp (stores masked later)
        const int colb = lin8 & 511;
        const float4 v = *reinterpret_cast<const float4*>(&A[(size_t)grow * IN_F + (colb >> 1)]);
        uint2 o;
        o.x = (unsigned)f2bf(v.x) | ((unsigned)f2bf(v.y) << 16);
        o.y = (unsigned)f2bf(v.z) | ((unsigned)f2bf(v.w) << 16);
        *reinterpret_cast<uint2*>(&At[lin8 ^ ((r_lin & 7) << 4)]) = o;
    }
    __syncthreads();

    const int lr = lane & 15;
    const int lg = lane >> 4;
    const int xr = (lr & 7) << 4;                     // swizzle term (row&7 == lr&7)
    const int klg = lg * 16;                          // byte k-chunk offset in row

    int rowbase[4];
#pragma unroll
    for (int m = 0; m < 4; ++m) rowbase[m] = (m * 16 + lr) * 512;

    const u16* bp = Bfrag + (size_t)wid * 16384 + lane * 8;

    f32x4 acc[4][4] = {};
#pragma unroll
    for (int ks = 0; ks < 8; ++ks) {
        bf16x8 af[4], bfr[4];
        const int kx = ((ks << 6) + klg) ^ xr;        // swizzled intra-row byte
#pragma unroll
        for (int n = 0; n < 4; ++n)
            bfr[n] = *reinterpret_cast<const bf16x8*>(&bp[ks * 2048 + n * 512]);
#pragma unroll
        for (int m = 0; m < 4; ++m)
            af[m] = *reinterpret_cast<const bf16x8*>(&At[rowbase[m] + kx]);
#pragma unroll
        for (int m = 0; m < 4; ++m)
#pragma unroll
            for (int n = 0; n < 4; ++n)
                acc[m][n] = __builtin_amdgcn_mfma_f32_16x16x32_bf16(bfr[n], af[m], acc[m][n], 0, 0, 0);
    }
    // acc[m][n][r]: value for node=row0+m*16+lr, channel (within group) n*16+lg*4+r

    if (wid < 4) {
        const int h = wid;
        float4 alv[4], arv[4];
#pragma unroll
        for (int n = 0; n < 4; ++n) {
            alv[n] = *reinterpret_cast<const float4*>(&a_l[h * D_HEAD + n * 16 + lg * 4]);
            arv[n] = *reinterpret_cast<const float4*>(&a_r[h * D_HEAD + n * 16 + lg * 4]);
        }
#pragma unroll
        for (int m = 0; m < 4; ++m) {
            const int node = row0 + m * 16 + lr;
            float dl = 0.f, dr = 0.f;
            u64 pk[4];
#pragma unroll
            for (int n = 0; n < 4; ++n) {
                float v0 = acc[m][n][0], v1 = acc[m][n][1], v2 = acc[m][n][2], v3 = acc[m][n][3];
                v0 = isnan(v0) ? 0.f : v0;            // nan_to_num
                v1 = isnan(v1) ? 0.f : v1;
                v2 = isnan(v2) ? 0.f : v2;
                v3 = isnan(v3) ? 0.f : v3;
                dl += v0 * alv[n].x + v1 * alv[n].y + v2 * alv[n].z + v3 * alv[n].w;
                dr += v0 * arv[n].x + v1 * arv[n].y + v2 * arv[n].z + v3 * arv[n].w;
                pk[n] = (u64)f2bf(v0) | ((u64)f2bf(v1) << 16) |
                        ((u64)f2bf(v2) << 32) | ((u64)f2bf(v3) << 48);
            }
            if (node < N_NODES) {
                const size_t base = (size_t)node * HD + h * D_HEAD + lg * 4;
#pragma unroll
                for (int n = 0; n < 4; ++n)
                    *reinterpret_cast<u64*>(&emb_bf[base + n * 16]) = pk[n];
            }
            dl += __shfl_xor(dl, 16, 64); dr += __shfl_xor(dr, 16, 64);
            dl += __shfl_xor(dl, 32, 64); dr += __shfl_xor(dr, 32, 64);
            if (lg == 0 && node < N_NODES) {
                s_l[node * H_HEADS + h] = dl;
                s_r[node * H_HEADS + h] = dr;
            }
        }
    } else {
        const int c0 = (wid - 4) * 64 + lg * 4;
        float4 rb[4];
#pragma unroll
        for (int n = 0; n < 4; ++n)
            rb[n] = *reinterpret_cast<const float4*>(&resb[c0 + n * 16]);
#pragma unroll
        for (int m = 0; m < 4; ++m) {
            const int node = row0 + m * 16 + lr;
            if (node < N_NODES) {
                const size_t base = (size_t)node * HD + c0;
#pragma unroll
                for (int n = 0; n < 4; ++n) {
                    float4 o;
                    o.x = acc[m][n][0] + rb[n].x;
                    o.y = acc[m][n][1] + rb[n].y;
                    o.z = acc[m][n][2] + rb[n].z;
                    o.w = acc[m][n][3] + rb[n].w;
                    *reinterpret_cast<float4*>(&outp[base + n * 16]) = o;
                }
            }
        }
    }
}

// ---------------- CSR build ----------------
__global__ void k_hist(const int* __restrict__ col, int* __restrict__ counts) {
    int e = blockIdx.x * 256 + threadIdx.x;
    if (e < E_EDGES) atomicAdd(&counts[col[e]], 1);
}

__global__ void k_scan1(const int* __restrict__ counts, int* __restrict__ row_ptr,
                        int* __restrict__ partials) {
    __shared__ int sd[256];
    const int t = threadIdx.x, b = blockIdx.x;
    const int base = b * 1024 + t * 4;
    int v[4];
#pragma unroll
    for (int j = 0; j < 4; ++j) v[j] = (base + j < N_NODES) ? counts[base + j] : 0;
    const int s = v[0] + v[1] + v[2] + v[3];
    sd[t] = s;
    __syncthreads();
    for (int off = 1; off < 256; off <<= 1) {
        int y = (t >= off) ? sd[t - off] : 0;
        __syncthreads();
        sd[t] += y;
        __syncthreads();
    }
    int p = sd[t] - s;
#pragma unroll
    for (int j = 0; j < 4; ++j) {
        if (base + j < N_NODES) row_ptr[base + j] = p;
        p += v[j];
    }
    if (t == 255) partials[b] = sd[255];
}

__global__ void k_scan2(int* __restrict__ partials) {
    __shared__ int sd[128];
    const int t = threadIdx.x;
    const int v = (t < 98) ? partials[t] : 0;
    sd[t] = v;
    __syncthreads();
    for (int off = 1; off < 128; off <<= 1) {
        int y = (t >= off) ? sd[t - off] : 0;
        __syncthreads();
        sd[t] += y;
        __syncthreads();
    }
    if (t < 98) partials[t] = sd[t] - v;
}

__global__ void k_scan3(int* __restrict__ row_ptr, int* __restrict__ fill,
                        const int* __restrict__ partials) {
    const int i = blockIdx.x * 256 + threadIdx.x;
    if (i < N_NODES) {
        const int v = row_ptr[i] + partials[i >> 10];
        row_ptr[i] = v;
        fill[i] = v;
    }
    if (i == 0) row_ptr[N_NODES] = E_EDGES;
}

__global__ void k_scatter(const int* __restrict__ row, const int* __restrict__ col,
                          const int* __restrict__ tp, int* __restrict__ fill,
                          int* __restrict__ perm) {
    int e = blockIdx.x * 256 + threadIdx.x;
    if (e < E_EDGES) {
        int c = col[e];
        int p = atomicAdd(&fill[c], 1);
        perm[p] = row[e] | (tp[e] << 20);   // row < 2^17, tp < 8
    }
}

// ---------------- K5: per-destination aggregation (one wave per node, 4-wide) -------------
__global__ __launch_bounds__(256)
void k_aggregate(const int* __restrict__ row_ptr, const int* __restrict__ perm,
                 const u16* __restrict__ emb_bf, const float* __restrict__ s_l,
                 const float* __restrict__ s_r, const float* __restrict__ s_e,
                 float* __restrict__ outp) {
    const int wave = threadIdx.x >> 6;
    const int lane = threadIdx.x & 63;
    const int n = blockIdx.x * 4 + wave;           // grid = N/4 exactly
    const int h = lane >> 4;                       // this lane's head
    const int start = row_ptr[n], end = row_ptr[n + 1];
    const float srh = s_r[n * H_HEADS + h];
    const size_t o = (size_t)n * HD + lane * 4;
    const float4 res = *reinterpret_cast<const float4*>(&outp[o]);   // hoisted: independent

    float se_h[NET_T];
#pragma unroll
    for (int t = 0; t < NET_T; ++t) se_h[t] = s_e[t * H_HEADS + h];

    float a0 = 0.f, a1 = 0.f, a2 = 0.f, a3 = 0.f, den = 0.f;
    int i = start;
    for (; i + 4 <= end; i += 4) {
        const int p0 = perm[i], p1 = perm[i + 1], p2 = perm[i + 2], p3 = perm[i + 3];
        const int r0 = p0 & 0xFFFFF, r1 = p1 & 0xFFFFF, r2 = p2 & 0xFFFFF, r3 = p3 & 0xFFFFF;
        const u64 ev0 = *reinterpret_cast<const u64*>(&emb_bf[(size_t)r0 * HD + lane * 4]);
        const u64 ev1 = *reinterpret_cast<const u64*>(&emb_bf[(size_t)r1 * HD + lane * 4]);
        const u64 ev2 = *reinterpret_cast<const u64*>(&emb_bf[(size_t)r2 * HD + lane * 4]);
        const u64 ev3 = *reinterpret_cast<const u64*>(&emb_bf[(size_t)r3 * HD + lane * 4]);
        const float sl0 = s_l[r0 * H_HEADS + h];
        const float sl1 = s_l[r1 * H_HEADS + h];
        const float sl2 = s_l[r2 * H_HEADS + h];
        const float sl3 = s_l[r3 * H_HEADS + h];
        float lg0 = sl0 + srh + se_h[p0 >> 20];
        float lg1 = sl1 + srh + se_h[p1 >> 20];
        float lg2 = sl2 + srh + se_h[p2 >> 20];
        float lg3 = sl3 + srh + se_h[p3 >> 20];
        lg0 = (lg0 > 0.f) ? lg0 : SLOPE * lg0;
        lg1 = (lg1 > 0.f) ? lg1 : SLOPE * lg1;
        lg2 = (lg2 > 0.f) ? lg2 : SLOPE * lg2;
        lg3 = (lg3 > 0.f) ? lg3 : SLOPE * lg3;
        const float ex0 = __expf(lg0), ex1 = __expf(lg1);
        const float ex2 = __expf(lg2), ex3 = __expf(lg3);
        a0 += ex0 * bf2f((unsigned)(ev0) & 0xFFFFu)       + ex1 * bf2f((unsigned)(ev1) & 0xFFFFu)
            + ex2 * bf2f((unsigned)(ev2) & 0xFFFFu)       + ex3 * bf2f((unsigned)(ev3) & 0xFFFFu);
        a1 += ex0 * bf2f((unsigned)(ev0 >> 16) & 0xFFFFu) + ex1 * bf2f((unsigned)(ev1 >> 16) & 0xFFFFu)
            + ex2 * bf2f((unsigned)(ev2 >> 16) & 0xFFFFu) + ex3 * bf2f((unsigned)(ev3 >> 16) & 0xFFFFu);
        a2 += ex0 * bf2f((unsigned)(ev0 >> 32) & 0xFFFFu) + ex1 * bf2f((unsigned)(ev1 >> 32) & 0xFFFFu)
            + ex2 * bf2f((unsigned)(ev2 >> 32) & 0xFFFFu) + ex3 * bf2f((unsigned)(ev3 >> 32) & 0xFFFFu);
        a3 += ex0 * bf2f((unsigned)(ev0 >> 48) & 0xFFFFu) + ex1 * bf2f((unsigned)(ev1 >> 48) & 0xFFFFu)
            + ex2 * bf2f((unsigned)(ev2 >> 48) & 0xFFFFu) + ex3 * bf2f((unsigned)(ev3 >> 48) & 0xFFFFu);
        den += ex0 + ex1 + ex2 + ex3;
    }
    for (; i < end; ++i) {
        const int p0 = perm[i];
        const int r0 = p0 & 0xFFFFF;
        const u64 ev0 = *reinterpret_cast<const u64*>(&emb_bf[(size_t)r0 * HD + lane * 4]);
        float lg0 = s_l[r0 * H_HEADS + h] + srh + se_h[p0 >> 20];
        lg0 = (lg0 > 0.f) ? lg0 : SLOPE * lg0;
        const float ex0 = __expf(lg0);
        a0 += ex0 * bf2f((unsigned)(ev0) & 0xFFFFu);
        a1 += ex0 * bf2f((unsigned)(ev0 >> 16) & 0xFFFFu);
        a2 += ex0 * bf2f((unsigned)(ev0 >> 32) & 0xFFFFu);
        a3 += ex0 * bf2f((unsigned)(ev0 >> 48) & 0xFFFFu);
        den += ex0;
    }
    const float inv = (den > 0.f) ? 1.f / den : 0.f;
    float4 out;
    float x;
    x = a0 * inv + res.x; out.x = (x > 0.f) ? x : expm1f(x);
    x = a1 * inv + res.y; out.y = (x > 0.f) ? x : expm1f(x);
    x = a2 * inv + res.z; out.z = (x > 0.f) ? x : expm1f(x);
    x = a3 * inv + res.w; out.w = (x > 0.f) ? x : expm1f(x);
    *reinterpret_cast<float4*>(&outp[o]) = out;
}

extern "C" void kernel_launch(void* const* d_in, const int* in_sizes, int n_in,
                              void* d_out, int out_size, void* d_ws, size_t ws_size,
                              hipStream_t stream) {
    const float* h    = (const float*)d_in[0];
    const float* W    = (const float*)d_in[1];
    const float* W_e  = (const float*)d_in[2];
    const float* eemb = (const float*)d_in[3];
    const float* a_l  = (const float*)d_in[4];
    const float* a_r  = (const float*)d_in[5];
    const float* a_e  = (const float*)d_in[6];
    const float* resW = (const float*)d_in[7];
    const float* resb = (const float*)d_in[8];
    const int* row = (const int*)d_in[9];
    const int* col = (const int*)d_in[10];
    const int* tp  = (const int*)d_in[11];
    float* outp = (float*)d_out;

    char* ws = (char*)d_ws;
    size_t off = 0;
    auto alloc = [&](size_t b) { size_t o = off; off += (b + 255) & ~(size_t)255; return o; };
    u16*  Bfrag   = (u16*)(ws + alloc((size_t)512 * IN_F * 2));
    u16*  emb_bf  = (u16*)(ws + alloc((size_t)N_NODES * HD * 2));
    float* s_l    = (float*)(ws + alloc((size_t)N_NODES * H_HEADS * 4));
    float* s_r    = (float*)(ws + alloc((size_t)N_NODES * H_HEADS * 4));
    float* s_e    = (float*)(ws + alloc(NET_T * H_HEADS * 4));
    int*  counts  = (int*)(ws + alloc((size_t)N_NODES * 4));
    int*  row_ptr = (int*)(ws + alloc((size_t)(N_NODES + 1) * 4));
    int*  fill    = (int*)(ws + alloc((size_t)N_NODES * 4));
    int*  perm    = (int*)(ws + alloc((size_t)E_EDGES * 4));
    int*  partials= (int*)(ws + alloc(128 * 4));

    k_se<<<1, 256, 0, stream>>>(eemb, W_e, a_e, s_e);
    k_prep_w<<<64, 256, 0, stream>>>(W, resW, Bfrag);
    k_mfma<<<(N_NODES + 63) / 64, 512, 0, stream>>>(h, Bfrag, a_l, a_r, resb, emb_bf, s_l, s_r, outp);
    hipMemsetAsync(counts, 0, (size_t)N_NODES * 4, stream);
    k_hist<<<(E_EDGES + 255) / 256, 256, 0, stream>>>(col, counts);
    k_scan1<<<98, 256, 0, stream>>>(counts, row_ptr, partials);
    k_scan2<<<1, 128, 0, stream>>>(partials);
    k_scan3<<<(N_NODES + 255) / 256, 256, 0, stream>>>(row_ptr, fill, partials);
    k_scatter<<<(E_EDGES + 255) / 256, 256, 0, stream>>>(row, col, tp, fill, perm);
    k_aggregate<<<N_NODES / 4, 256, 0, stream>>>(row_ptr, perm, emb_bf, s_l, s_r, s_e, outp);
}